// Round 17
// baseline (287.357 us; speedup 1.0000x reference)
//
#include <hip/hip_runtime.h>
#include <cstdint>
#include <cstddef>

#define BB 2
#define NN 8192
#define CC 128
#define KK 16
#define EPSV 1e-5f
#define GRP 16      // candidate groups
#define GPTS 512    // points per group
#define GCAP 32     // per-(query,group) segment capacity (list = 32MB exactly)

typedef unsigned long long u64;
typedef unsigned int u32;
typedef unsigned short ushort_t;
typedef short short8v __attribute__((ext_vector_type(8)));
typedef float f32x4 __attribute__((ext_vector_type(4)));

__device__ __forceinline__ float med3f(float x, float y, float z) {
  float r;
  asm("v_med3_f32 %0, %1, %2, %3" : "=v"(r) : "v"(x), "v"(y), "v"(z));
  return r;
}

// ---------------- prep: pack (x,y,z, sq) ----------------
__global__ __launch_bounds__(256) void k_prep(const float* __restrict__ xyz,
                                              float4* __restrict__ xyzw) {
  int t = blockIdx.x * 256 + threadIdx.x;
  if (t >= BB * NN) return;
  float x = xyz[t * 3 + 0], y = xyz[t * 3 + 1], z = xyz[t * 3 + 2];
  float sq = __fadd_rn(__fadd_rn(__fmul_rn(x, x), __fmul_rn(y, y)), __fmul_rn(z, z));
  xyzw[t] = make_float4(x, y, z, sq);
}

// EXACT reference-rounded distance (defines the selected set)
__device__ __forceinline__ float distf(const float4& q, const float4& c) {
  float dot = __fadd_rn(__fadd_rn(__fmul_rn(q.x, c.x), __fmul_rn(q.y, c.y)),
                        __fmul_rn(q.z, c.z));
  float d = __fsub_rn(__fadd_rn(q.w, c.w), __fmul_rn(2.0f, dot));
  return fmaxf(d, 0.0f);
}

// FMA screening distance: p = (-2x,-2y,-2z, sq). |dq - d_exact| <~ 3e-5.
__device__ __forceinline__ float distq(const float4& p, const float4& c) {
  return fmaf(p.z, c.z, fmaf(p.y, c.y, fmaf(p.x, c.x, p.w + c.w)));
}

// ---------------- KNN A: certified per-query threshold from 1024-sample -------
__global__ __launch_bounds__(256) void k_thr(const float4* __restrict__ xyzw,
                                             float* __restrict__ thr) {
  __shared__ float part[16][16][16];
  const int tid = threadIdx.x;
  const int qloc = tid & 15;
  const int s = tid >> 4;
  const int n = blockIdx.x * 16 + qloc;
  const int b = n >> 13;
  const float4 q = xyzw[n];
  const float4 p = make_float4(-2.f * q.x, -2.f * q.y, -2.f * q.z, q.w);
  const float4* base = xyzw + b * NN;
  float a[KK];
#pragma unroll
  for (int i = 0; i < KK; ++i) a[i] = 3.4e38f;
  const int j0 = s * 64;
#pragma unroll 4
  for (int i = 0; i < 64; ++i) {
    const float4 c = base[(j0 + i) * 8];
    const float d = distq(p, c);
#pragma unroll
    for (int k = KK - 1; k >= 1; --k) a[k] = med3f(d, a[k - 1], a[k]);
    a[0] = fminf(d, a[0]);
  }
#pragma unroll
  for (int i = 0; i < KK; ++i) part[qloc][s][i] = a[i];
  __syncthreads();
  if (s < 4) {
#pragma unroll
    for (int ss = 1; ss < 4; ++ss)
#pragma unroll
      for (int i = 0; i < KK; ++i) {
        const float d = part[qloc][s + ss * 4][i];
#pragma unroll
        for (int k = KK - 1; k >= 1; --k) a[k] = med3f(d, a[k - 1], a[k]);
        a[0] = fminf(d, a[0]);
      }
#pragma unroll
    for (int i = 0; i < KK; ++i) part[qloc][s][i] = a[i];
  }
  __syncthreads();
  if (s == 0) {
#pragma unroll
    for (int ss = 1; ss < 4; ++ss)
#pragma unroll
      for (int i = 0; i < KK; ++i) {
        const float d = part[qloc][ss][i];
#pragma unroll
        for (int k = KK - 1; k >= 1; --k) a[k] = med3f(d, a[k - 1], a[k]);
        a[0] = fminf(d, a[0]);
      }
    const float t = a[KK - 1];
    thr[n] = t + (5e-4f + 4e-5f * fabsf(t));  // covers both screen epsilons
  }
}

// ---------------- KNN B: atomic-free collect (thread owns (query,group)) ------
__global__ __launch_bounds__(256) void k_collect(const float4* __restrict__ xyzw,
                                                 const float* __restrict__ thr,
                                                 u32* __restrict__ cnt8,
                                                 u32* __restrict__ list) {
  __shared__ float4 pts[GPTS];
  const int tid = threadIdx.x;
  const int n = blockIdx.x * 256 + tid;
  const int b = n >> 13;
  const int g = blockIdx.y;
  const int m0 = g * GPTS;
#pragma unroll
  for (int i = 0; i < GPTS / 256; ++i)
    pts[i * 256 + tid] = xyzw[b * NN + m0 + i * 256 + tid];
  const float4 q = xyzw[n];
  const float4 p = make_float4(-2.f * q.x, -2.f * q.y, -2.f * q.z, q.w);
  const float tn = thr[n];
  __syncthreads();
  u32* seg = list + ((size_t)n * GRP + g) * GCAP;
  int cnt = 0;
#pragma unroll 4
  for (int mi = 0; mi < GPTS; ++mi) {
    const float d = distq(p, pts[mi]);  // LDS broadcast read
    if (d <= tn) {
      if (cnt < GCAP) seg[cnt] = (u32)(m0 + mi);
      ++cnt;
    }
  }
  cnt8[n * GRP + g] = (u32)cnt;
}

// ---------------- KNN C: exact finalize over ~128 collected ----------------
__global__ __launch_bounds__(256) void k_fin(const float4* __restrict__ xyzw,
                                             const u32* __restrict__ cnt8,
                                             const u32* __restrict__ list,
                                             int* __restrict__ idx) {
  __shared__ double part[16][16][16];
  const int tid = threadIdx.x;
  const int qloc = tid & 15;
  const int s = tid >> 4;
  const int n = blockIdx.x * 16 + qloc;
  const int b = n >> 13;
  const float4 q = xyzw[n];
  const int cn = (int)cnt8[n * GRP + s];
  const int cl = (cn < GCAP) ? cn : GCAP;
  const u32* L = list + ((size_t)n * GRP + s) * GCAP;
  double keys[KK];
#pragma unroll
  for (int i = 0; i < KK; ++i) keys[i] = __longlong_as_double(0x7FEFFFFFFFFFFFFFLL);
  for (int j = 0; j < cl; ++j) {
    const u32 m = L[j];
    const float d = distf(q, xyzw[b * NN + m]);
    u64 kb_ = ((u64)__float_as_uint(d) << 32) | m;
    double kd = __longlong_as_double((long long)kb_);
    if (kd < keys[KK - 1]) {
#pragma unroll
      for (int i = 0; i < KK; ++i) {
        double lo = fmin(keys[i], kd);
        kd = fmax(keys[i], kd);
        keys[i] = lo;
      }
    }
  }
#pragma unroll
  for (int i = 0; i < KK; ++i) part[qloc][s][i] = keys[i];
  __syncthreads();
  if (s < 4) {
#pragma unroll
    for (int ss = 1; ss < 4; ++ss)
#pragma unroll
      for (int i = 0; i < KK; ++i) {
        double kd = part[qloc][s + ss * 4][i];
        if (kd < keys[KK - 1]) {
#pragma unroll
          for (int k = 0; k < KK; ++k) {
            double lo = fmin(keys[k], kd);
            kd = fmax(keys[k], kd);
            keys[k] = lo;
          }
        }
      }
#pragma unroll
    for (int i = 0; i < KK; ++i) part[qloc][s][i] = keys[i];
  }
  __syncthreads();
  if (s == 0) {
#pragma unroll
    for (int ss = 1; ss < 4; ++ss)
#pragma unroll
      for (int i = 0; i < KK; ++i) {
        double kd = part[qloc][ss][i];
        if (kd < keys[KK - 1]) {
#pragma unroll
          for (int k = 0; k < KK; ++k) {
            double lo = fmin(keys[k], kd);
            kd = fmax(keys[k], kd);
            keys[k] = lo;
          }
        }
      }
    bool ovf = false;
#pragma unroll
    for (int gg = 0; gg < GRP; ++gg) ovf |= (cnt8[n * GRP + gg] > GCAP);
    if (ovf) {  // pathological: exact full rescan (deterministic trigger)
#pragma unroll
      for (int i = 0; i < KK; ++i) keys[i] = __longlong_as_double(0x7FEFFFFFFFFFFFFFLL);
      for (int mi = 0; mi < NN; ++mi) {
        const float d = distf(q, xyzw[b * NN + mi]);
        u64 kb_ = ((u64)__float_as_uint(d) << 32) | (u32)mi;
        double kd = __longlong_as_double((long long)kb_);
        if (kd < keys[KK - 1]) {
#pragma unroll
          for (int k = 0; k < KK; ++k) {
            double lo = fmin(keys[k], kd);
            kd = fmax(keys[k], kd);
            keys[k] = lo;
          }
        }
      }
    }
#pragma unroll
    for (int j = 0; j < KK; ++j)
      idx[n * KK + j] = (int)((u64)__double_as_longlong(keys[j]) & 0xffffffffu);
  }
}

// ---------------- weight folding: Wd = aW1 @ Wsrc ----------------
__global__ __launch_bounds__(128) void k_fold(const float* __restrict__ aW1,
                                              const float* __restrict__ Wq,
                                              const float* __restrict__ Wk,
                                              const float* __restrict__ pW2,
                                              const float* __restrict__ pb2,
                                              float* __restrict__ WqA,
                                              float* __restrict__ WkA,
                                              float* __restrict__ WpA,
                                              float* __restrict__ tvec) {
  const int bx = blockIdx.x;
  const int j = threadIdx.x;
  if (bx == 48) {
    float s = 0.f;
    for (int i = 0; i < 128; ++i) s = fmaf(aW1[j * 128 + i], pb2[i], s);
    tvec[j] = s;
    return;
  }
  const int mat = bx >> 4;
  const int c0 = (bx & 15) * 8;
  const float* S = (mat == 0) ? Wq : (mat == 1) ? Wk : pW2;
  float* D = (mat == 0) ? WqA : (mat == 1) ? WkA : WpA;
  float acc[8];
#pragma unroll
  for (int r = 0; r < 8; ++r) acc[r] = 0.f;
  for (int i = 0; i < 128; ++i) {
    float sv = S[i * 128 + j];
#pragma unroll
    for (int r = 0; r < 8; ++r) acc[r] = fmaf(aW1[(c0 + r) * 128 + i], sv, acc[r]);
  }
#pragma unroll
  for (int r = 0; r < 8; ++r) D[(c0 + r) * 128 + j] = acc[r];
}

// ---------------- split-bf16 helpers ----------------
__device__ __forceinline__ void splitf(float a, ushort_t& h, ushort_t& l) {
  u32 ab = __float_as_uint(a);
  h = (ushort_t)(ab >> 16);
  float hif = __uint_as_float(ab & 0xffff0000u);
  l = (ushort_t)(__float_as_uint(a - hif) >> 16);
}

// pack W [128][128] fp32 -> frag-ordered split planes (7 matrices)
__global__ __launch_bounds__(256) void k_packw(
    const float* __restrict__ S0, const float* __restrict__ S1,
    const float* __restrict__ S2, const float* __restrict__ S3,
    const float* __restrict__ S4, const float* __restrict__ S5,
    const float* __restrict__ S6, ushort_t* __restrict__ Phall,
    ushort_t* __restrict__ Plall) {
  const int bx = blockIdx.x;
  const int mat = bx >> 3;
  const int T = bx & 7;
  const float* S;
  switch (mat) {
    case 0: S = S0; break;
    case 1: S = S1; break;
    case 2: S = S2; break;
    case 3: S = S3; break;
    case 4: S = S4; break;
    case 5: S = S5; break;
    default: S = S6; break;
  }
  const int tid = threadIdx.x;
  const int s = tid >> 4;
  const int lr = tid & 15;
  const int c = T * 16 + lr;
  short8v vh, vl;
#pragma unroll
  for (int e = 0; e < 8; ++e) {
    ushort_t hh, ll;
    splitf(S[c * 128 + s * 8 + e], hh, ll);
    vh[e] = (short)hh;
    vl[e] = (short)ll;
  }
  const int po = mat * 16384 + T * 2048 + s * 128 + lr * 8;
  *(short8v*)&Phall[po] = vh;
  *(short8v*)&Plall[po] = vl;
}

// stage R rows x 128 cols fp32 -> hi/lo bf16 planes in LDS, XOR-swizzled
template <int ITERS>
__device__ __forceinline__ void stage_rows(const float4* __restrict__ G4,
                                           ushort_t* Bh, ushort_t* Bl, int tid) {
#pragma unroll
  for (int i = 0; i < ITERS; ++i) {
    int f = i * 256 + tid;
    int r = f >> 5, k4 = f & 31;
    float4 v = G4[f];
    ushort_t h0, l0, h1, l1, h2, l2, h3, l3;
    splitf(v.x, h0, l0);
    splitf(v.y, h1, l1);
    splitf(v.z, h2, l2);
    splitf(v.w, h3, l3);
    int slot = k4 >> 1;
    int sub = (k4 & 1) * 4;
    int base = r * 128 + ((slot ^ (r & 15)) * 8) + sub;
    *(uint2*)&Bh[base] = make_uint2((u32)h0 | ((u32)h1 << 16), (u32)h2 | ((u32)h3 << 16));
    *(uint2*)&Bl[base] = make_uint2((u32)l0 | ((u32)l1 << 16), (u32)l2 | ((u32)l3 << 16));
  }
}

// 64-row LDS-A x GLOBAL-packed-W split GEMM (k_fused)
__device__ __forceinline__ void gemm64g(const ushort_t* ABh, const ushort_t* ABl,
                                        const ushort_t* __restrict__ Ph,
                                        const ushort_t* __restrict__ Pl,
                                        f32x4 acc[2][4], int tid) {
  const int l = tid & 63, wid = tid >> 6;
  const int wrow = wid >> 1, wcol = wid & 1;
  const int lq = l >> 4, lr = l & 15;
#pragma unroll
  for (int ks = 0; ks < 4; ++ks) {
    const int sw8 = (((ks * 4 + lq) ^ lr) * 8);
    short8v ah[2], al[2], wh[4], wl[4];
#pragma unroll
    for (int ct = 0; ct < 4; ++ct) {
      int off = (wcol * 4 + ct) * 2048 + (ks * 4 + lq) * 128 + lr * 8;
      wh[ct] = *(const short8v*)&Ph[off];
      wl[ct] = *(const short8v*)&Pl[off];
    }
#pragma unroll
    for (int rt = 0; rt < 2; ++rt) {
      int row = wrow * 32 + rt * 16 + lr;
      ah[rt] = *(const short8v*)&ABh[row * 128 + sw8];
      al[rt] = *(const short8v*)&ABl[row * 128 + sw8];
    }
    __builtin_amdgcn_s_setprio(1);
#pragma unroll
    for (int rt = 0; rt < 2; ++rt)
#pragma unroll
      for (int ct = 0; ct < 4; ++ct) {
        acc[rt][ct] = __builtin_amdgcn_mfma_f32_16x16x32_bf16(ah[rt], wh[ct], acc[rt][ct], 0, 0, 0);
        acc[rt][ct] = __builtin_amdgcn_mfma_f32_16x16x32_bf16(ah[rt], wl[ct], acc[rt][ct], 0, 0, 0);
        acc[rt][ct] = __builtin_amdgcn_mfma_f32_16x16x32_bf16(al[rt], wh[ct], acc[rt][ct], 0, 0, 0);
      }
    __builtin_amdgcn_s_setprio(0);
  }
}

// ---------------- 16-row GEMM, W streamed from packed planes (1024 blocks) ----
template <int NW>
__global__ __launch_bounds__(256) void k_mms(const float* __restrict__ A,
                                             const ushort_t* __restrict__ Phall,
                                             const ushort_t* __restrict__ Plall,
                                             int m0, float* __restrict__ C0,
                                             float* __restrict__ C1,
                                             float* __restrict__ C2) {
  __shared__ ushort_t ABh[16 * 128], ABl[16 * 128];
  const int tid = threadIdx.x;
  const int Rbase = blockIdx.x * 16;
  stage_rows<2>((const float4*)(A + (size_t)Rbase * 128), ABh, ABl, tid);
  __syncthreads();
  const int l = tid & 63, wid = tid >> 6;
  const int lq = l >> 4, lr = l & 15;
  float* Cs[3] = {C0, C1, C2};
#pragma unroll
  for (int w = 0; w < NW; ++w) {
    const ushort_t* Ph = Phall + (size_t)(m0 + w) * 16384;
    const ushort_t* Pl = Plall + (size_t)(m0 + w) * 16384;
    f32x4 acc[2];
#pragma unroll
    for (int ct = 0; ct < 2; ++ct) acc[ct] = (f32x4)0.f;
#pragma unroll
    for (int ks = 0; ks < 4; ++ks) {
      const int sw8 = (((ks * 4 + lq) ^ lr) * 8);
      short8v ah, al, wh[2], wl[2];
#pragma unroll
      for (int ct = 0; ct < 2; ++ct) {
        int off = (wid * 2 + ct) * 2048 + (ks * 4 + lq) * 128 + lr * 8;
        wh[ct] = *(const short8v*)&Ph[off];
        wl[ct] = *(const short8v*)&Pl[off];
      }
      ah = *(const short8v*)&ABh[lr * 128 + sw8];
      al = *(const short8v*)&ABl[lr * 128 + sw8];
#pragma unroll
      for (int ct = 0; ct < 2; ++ct) {
        acc[ct] = __builtin_amdgcn_mfma_f32_16x16x32_bf16(ah, wh[ct], acc[ct], 0, 0, 0);
        acc[ct] = __builtin_amdgcn_mfma_f32_16x16x32_bf16(ah, wl[ct], acc[ct], 0, 0, 0);
        acc[ct] = __builtin_amdgcn_mfma_f32_16x16x32_bf16(al, wh[ct], acc[ct], 0, 0, 0);
      }
    }
#pragma unroll
    for (int ct = 0; ct < 2; ++ct) {
      int c = (wid * 2 + ct) * 16 + lr;
#pragma unroll
      for (int reg = 0; reg < 4; ++reg) {
        int R = Rbase + lq * 4 + reg;
        Cs[w][(size_t)R * 128 + c] = acc[ct][reg];
      }
    }
  }
}

// ---------------- fused chain (64 rows / 4 queries per block) ----------------
// Final Wout projection fused in-block: O-tile (4 queries) staged into the dead
// z-plane LDS rows 0..3, mini-GEMM vs packed plane 6 -> writes d_out directly.
__global__ __launch_bounds__(256, 4) void k_fused(
    const float4* __restrict__ xyzw, const int* __restrict__ idx,
    const float* __restrict__ qbA, const float* __restrict__ kbA,
    const float* __restrict__ vb, const float* __restrict__ pW1,
    const float* __restrict__ pb1, const float* __restrict__ pg,
    const float* __restrict__ pbeta, const float* __restrict__ pm,
    const float* __restrict__ pv, const float* __restrict__ pb2,
    const float* __restrict__ ab1, const float* __restrict__ ag,
    const float* __restrict__ abeta, const float* __restrict__ am,
    const float* __restrict__ av, const float* __restrict__ ab2,
    const float* __restrict__ tvec, const ushort_t* __restrict__ Phall,
    const ushort_t* __restrict__ Plall, float* __restrict__ out) {
  __shared__ ushort_t ABh[64 * 128], ABl[64 * 128];
  __shared__ float4 fW1[128];
  __shared__ float sA[128], tA[128], pB2[128], aB2[128];
  __shared__ int idxs[64];
  const int tid = threadIdx.x;
  const int Qbase = blockIdx.x * 4;
  const int b = Qbase >> 13;

  if (tid < 64) idxs[tid] = idx[Qbase * KK + tid];
  if (tid < 128) {
    int c = tid;
    float s1 = pg[c] / sqrtf(pv[c] + EPSV);
    fW1[c] = make_float4(pW1[c * 3] * s1, pW1[c * 3 + 1] * s1, pW1[c * 3 + 2] * s1,
                         (pb1[c] - pm[c]) * s1 + pbeta[c]);
    float s2 = ag[c] / sqrtf(av[c] + EPSV);
    sA[c] = s2;
    tA[c] = fmaf(s2, ab1[c] + tvec[c] - am[c], abeta[c]);
    pB2[c] = pb2[c];
    aB2[c] = ab2[c];
  }
  __syncthreads();

  // h1 tile (64 rows) -> A planes
  {
    int r = tid >> 2, qq = tid & 3;
    int Q = Qbase + (r >> 4);
    int m = idxs[r];
    float4 pq = xyzw[Q];
    float4 pn = xyzw[b * NN + m];
    float rx = pn.x - pq.x, ry = pn.y - pq.y, rz = pn.z - pq.z;
#pragma unroll
    for (int g = 0; g < 4; ++g) {
      short8v vh, vl;
      int c0 = qq * 32 + g * 8;
#pragma unroll
      for (int e = 0; e < 8; ++e) {
        float4 w = fW1[c0 + e];
        float h = fmaxf(fmaf(rz, w.z, fmaf(ry, w.y, fmaf(rx, w.x, w.w))), 0.f);
        ushort_t hh, ll;
        splitf(h, hh, ll);
        vh[e] = (short)hh;
        vl[e] = (short)ll;
      }
      int sw = (c0 >> 3) ^ (r & 15);
      *(short8v*)&ABh[r * 128 + sw * 8] = vh;
      *(short8v*)&ABl[r * 128 + sw * 8] = vl;
    }
  }
  __syncthreads();

  const int l = tid & 63, wid = tid >> 6;
  const int wrow = wid >> 1, wcol = wid & 1;
  const int lq = l >> 4, lr = l & 15;

  // GEMM0a: pos = h1 @ pW2^T (held); GEMM0b: posA = h1 @ WpA^T (held)
  f32x4 pos_[2][4], pa_[2][4];
#pragma unroll
  for (int rt = 0; rt < 2; ++rt)
#pragma unroll
    for (int ct = 0; ct < 4; ++ct) {
      pos_[rt][ct] = (f32x4)0.f;
      pa_[rt][ct] = (f32x4)0.f;
    }
  gemm64g(ABh, ABl, Phall, Plall, pos_, tid);
  gemm64g(ABh, ABl, Phall + 16384, Plall + 16384, pa_, tid);
  __syncthreads();

  // z = relu(s * (qA_gather - kA_gather + posA) + t) -> A planes
#pragma unroll
  for (int rt = 0; rt < 2; ++rt) {
    int qi_loc = wrow * 2 + rt;
    int Q = Qbase + qi_loc;
    int mr[4];
#pragma unroll
    for (int reg = 0; reg < 4; ++reg) mr[reg] = b * NN + idxs[qi_loc * 16 + lq * 4 + reg];
#pragma unroll
    for (int ct = 0; ct < 4; ++ct) {
      int c = wcol * 64 + ct * 16 + lr;
      float qv = qbA[(size_t)Q * 128 + c];
      float sc = sA[c], tc = tA[c];
#pragma unroll
      for (int reg = 0; reg < 4; ++reg) {
        float u = qv - kbA[(size_t)mr[reg] * 128 + c] + pa_[rt][ct][reg];
        float z = fmaxf(fmaf(u, sc, tc), 0.f);
        ushort_t hh, ll;
        splitf(z, hh, ll);
        int R15 = lq * 4 + reg;
        int row = wrow * 32 + rt * 16 + R15;
        int base = row * 128 + (((c >> 3) ^ R15) * 8) + (c & 7);
        ABh[base] = hh;
        ABl[base] = ll;
      }
    }
  }
  __syncthreads();

  // GEMM2: logits = z @ aW2^T (+ab2); softmax over 16 neighbors -> oo[rt][ct]
  f32x4 acc[2][4];
#pragma unroll
  for (int rt = 0; rt < 2; ++rt)
#pragma unroll
    for (int ct = 0; ct < 4; ++ct) acc[rt][ct] = (f32x4)0.f;
  gemm64g(ABh, ABl, Phall + 32768, Plall + 32768, acc, tid);

  float oo[2][4];
#pragma unroll
  for (int rt = 0; rt < 2; ++rt) {
    int qi_loc = wrow * 2 + rt;
    int mr[4];
#pragma unroll
    for (int reg = 0; reg < 4; ++reg) mr[reg] = b * NN + idxs[qi_loc * 16 + lq * 4 + reg];
#pragma unroll
    for (int ct = 0; ct < 4; ++ct) {
      int c = wcol * 64 + ct * 16 + lr;
      float ab2v = aB2[c];
      float lg[4];
#pragma unroll
      for (int reg = 0; reg < 4; ++reg) lg[reg] = acc[rt][ct][reg] + ab2v;
      float mx = fmaxf(fmaxf(lg[0], lg[1]), fmaxf(lg[2], lg[3]));
      mx = fmaxf(mx, __shfl_xor(mx, 16));
      mx = fmaxf(mx, __shfl_xor(mx, 32));
      float s = 0.f, o = 0.f;
      float pb2v = pB2[c];
#pragma unroll
      for (int reg = 0; reg < 4; ++reg) {
        float e_ = expf(lg[reg] - mx);
        s += e_;
        float vv = vb[(size_t)mr[reg] * 128 + c] + pos_[rt][ct][reg] + pb2v;
        o = fmaf(e_, vv, o);
      }
      s += __shfl_xor(s, 16);
      s += __shfl_xor(s, 32);
      o += __shfl_xor(o, 16);
      o += __shfl_xor(o, 32);
      oo[rt][ct] = o / s;  // uniform across lq after reductions
    }
  }

  // O-tile (4 queries x 128) -> A-plane rows 0..3 (rows 4..15 hold stale finite
  // z values; their MFMA outputs are simply never stored).
  __syncthreads();  // all waves finished reading the z-tile
  if (lq == 0) {
#pragma unroll
    for (int rt = 0; rt < 2; ++rt) {
      int row = wrow * 2 + rt;
#pragma unroll
      for (int ct = 0; ct < 4; ++ct) {
        int c = wcol * 64 + ct * 16 + lr;
        ushort_t hh, ll;
        splitf(oo[rt][ct], hh, ll);
        int base = row * 128 + (((c >> 3) ^ row) * 8) + (c & 7);
        ABh[base] = hh;
        ABl[base] = ll;
      }
    }
  }
  __syncthreads();

  // final: out[Q] = O @ Wout^T (packed plane 6); same split order as k_mms.
  const ushort_t* Ph6 = Phall + 6 * 16384;
  const ushort_t* Pl6 = Plall + 6 * 16384;
  f32x4 fo[2];
  fo[0] = (f32x4)0.f;
  fo[1] = (f32x4)0.f;
#pragma unroll
  for (int ks = 0; ks < 4; ++ks) {
    const int sw8 = (((ks * 4 + lq) ^ lr) * 8);
    short8v ah = *(const short8v*)&ABh[lr * 128 + sw8];
    short8v al = *(const short8v*)&ABl[lr * 128 + sw8];
#pragma unroll
    for (int ct = 0; ct < 2; ++ct) {
      int off2 = (wid * 2 + ct) * 2048 + (ks * 4 + lq) * 128 + lr * 8;
      short8v wh = *(const short8v*)&Ph6[off2];
      short8v wl = *(const short8v*)&Pl6[off2];
      fo[ct] = __builtin_amdgcn_mfma_f32_16x16x32_bf16(ah, wh, fo[ct], 0, 0, 0);
      fo[ct] = __builtin_amdgcn_mfma_f32_16x16x32_bf16(ah, wl, fo[ct], 0, 0, 0);
      fo[ct] = __builtin_amdgcn_mfma_f32_16x16x32_bf16(al, wh, fo[ct], 0, 0, 0);
    }
  }
  if (lq == 0) {
#pragma unroll
    for (int ct = 0; ct < 2; ++ct) {
      int c = (wid * 2 + ct) * 16 + lr;
#pragma unroll
      for (int reg = 0; reg < 4; ++reg)
        out[(size_t)(Qbase + reg) * 128 + c] = fo[ct][reg];
    }
  }
}

// ---------------- host launch ----------------
extern "C" void kernel_launch(void* const* d_in, const int* in_sizes, int n_in,
                              void* d_out, int out_size, void* d_ws, size_t ws_size,
                              hipStream_t stream) {
  const float* xyz = (const float*)d_in[0];
  const float* feat = (const float*)d_in[1];
  const float* Wq = (const float*)d_in[2];
  const float* Wk = (const float*)d_in[3];
  const float* Wv = (const float*)d_in[4];
  const float* pW1 = (const float*)d_in[5];
  const float* pb1 = (const float*)d_in[6];
  const float* pg = (const float*)d_in[7];
  const float* pbeta = (const float*)d_in[8];
  const float* pmean = (const float*)d_in[9];
  const float* pvar = (const float*)d_in[10];
  const float* pW2 = (const float*)d_in[11];
  const float* pb2 = (const float*)d_in[12];
  const float* aW1 = (const float*)d_in[13];
  const float* ab1 = (const float*)d_in[14];
  const float* ag = (const float*)d_in[15];
  const float* abeta = (const float*)d_in[16];
  const float* amean = (const float*)d_in[17];
  const float* avar = (const float*)d_in[18];
  const float* aW2 = (const float*)d_in[19];
  const float* ab2 = (const float*)d_in[20];
  const float* Wout = (const float*)d_in[21];
  float* out = (float*)d_out;
  char* ws = (char*)d_ws;

  size_t off = 0;
  auto alloc = [&](size_t bytes) {
    size_t r = off;
    off += (bytes + 255) & ~(size_t)255;
    return r;
  };
  float4* xyzw = (float4*)(ws + alloc((size_t)BB * NN * 16));
  int* idx = (int*)(ws + alloc((size_t)BB * NN * KK * 4));
  size_t o_qb = alloc((size_t)BB * NN * CC * 4);
  size_t o_kb = alloc((size_t)BB * NN * CC * 4);
  size_t o_vb = alloc((size_t)BB * NN * CC * 4);
  size_t o_ob = alloc((size_t)BB * NN * CC * 4);  // keeps list span intact
  float* qbA = (float*)(ws + o_qb);
  float* kbA = (float*)(ws + o_kb);
  float* vb = (float*)(ws + o_vb);
  (void)o_ob;
  // KNN list aliases qbA..(o_ob end): 16384 * GRP(16) * GCAP(32) * 4B = 32 MB
  u32* list = (u32*)(ws + o_qb);
  // folded weights + packed planes + thresholds + counts (live whole run)
  float* WqA = (float*)(ws + alloc(128 * 128 * 4));
  float* WkA = (float*)(ws + alloc(128 * 128 * 4));
  float* WpA = (float*)(ws + alloc(128 * 128 * 4));
  float* tvec = (float*)(ws + alloc(128 * 4));
  ushort_t* Phall = (ushort_t*)(ws + alloc(7 * 16384 * 2));
  ushort_t* Plall = (ushort_t*)(ws + alloc(7 * 16384 * 2));
  float* thrbuf = (float*)(ws + alloc((size_t)BB * NN * 4));
  u32* cnt8 = (u32*)(ws + alloc((size_t)BB * NN * GRP * 4));

  k_prep<<<(BB * NN) / 256, 256, 0, stream>>>(xyz, xyzw);
  k_fold<<<49, 128, 0, stream>>>(aW1, Wq, Wk, pW2, pb2, WqA, WkA, WpA, tvec);
  // planes: 0=pW2 1=WpA 2=aW2 3=WqA 4=WkA 5=Wv 6=Wout
  k_packw<<<56, 256, 0, stream>>>(pW2, WpA, aW2, WqA, WkA, Wv, Wout, Phall, Plall);

  k_thr<<<(BB * NN) / 16, 256, 0, stream>>>(xyzw, thrbuf);
  k_collect<<<dim3((BB * NN) / 256, GRP), 256, 0, stream>>>(xyzw, thrbuf, cnt8, list);
  k_fin<<<(BB * NN) / 16, 256, 0, stream>>>(xyzw, cnt8, list, idx);

  k_mms<3><<<(BB * NN) / 16, 256, 0, stream>>>(feat, Phall, Plall, 3, qbA, kbA, vb);

  k_fused<<<(BB * NN * KK) / 64, 256, 0, stream>>>(
      xyzw, idx, qbA, kbA, vb, pW1, pb1, pg, pbeta, pmean, pvar, pb2, ab1, ag,
      abeta, amean, avar, ab2, tvec, Phall, Plall, out);
}

// Round 18
// 242.786 us; speedup vs baseline: 1.1836x; 1.1836x over previous
//
#include <hip/hip_runtime.h>
#include <cstdint>
#include <cstddef>

#define BB 2
#define NN 8192
#define CC 128
#define KK 16
#define EPSV 1e-5f
#define GRP 16      // candidate groups
#define GPTS 512    // points per group
#define GCAP 32     // per-(query,group) segment capacity (list = 32MB exactly)

typedef unsigned long long u64;
typedef unsigned int u32;
typedef unsigned short ushort_t;
typedef short short8v __attribute__((ext_vector_type(8)));
typedef float f32x4 __attribute__((ext_vector_type(4)));

__device__ __forceinline__ float med3f(float x, float y, float z) {
  float r;
  asm("v_med3_f32 %0, %1, %2, %3" : "=v"(r) : "v"(x), "v"(y), "v"(z));
  return r;
}

// ---------------- prep: pack (x,y,z, sq) ----------------
__global__ __launch_bounds__(256) void k_prep(const float* __restrict__ xyz,
                                              float4* __restrict__ xyzw) {
  int t = blockIdx.x * 256 + threadIdx.x;
  if (t >= BB * NN) return;
  float x = xyz[t * 3 + 0], y = xyz[t * 3 + 1], z = xyz[t * 3 + 2];
  float sq = __fadd_rn(__fadd_rn(__fmul_rn(x, x), __fmul_rn(y, y)), __fmul_rn(z, z));
  xyzw[t] = make_float4(x, y, z, sq);
}

// EXACT reference-rounded distance (defines the selected set)
__device__ __forceinline__ float distf(const float4& q, const float4& c) {
  float dot = __fadd_rn(__fadd_rn(__fmul_rn(q.x, c.x), __fmul_rn(q.y, c.y)),
                        __fmul_rn(q.z, c.z));
  float d = __fsub_rn(__fadd_rn(q.w, c.w), __fmul_rn(2.0f, dot));
  return fmaxf(d, 0.0f);
}

// FMA screening distance: p = (-2x,-2y,-2z, sq). |dq - d_exact| <~ 3e-5.
__device__ __forceinline__ float distq(const float4& p, const float4& c) {
  return fmaf(p.z, c.z, fmaf(p.y, c.y, fmaf(p.x, c.x, p.w + c.w)));
}

// ---------------- KNN A: certified per-query threshold from 1024-sample -------
__global__ __launch_bounds__(256) void k_thr(const float4* __restrict__ xyzw,
                                             float* __restrict__ thr) {
  __shared__ float part[16][16][16];
  const int tid = threadIdx.x;
  const int qloc = tid & 15;
  const int s = tid >> 4;
  const int n = blockIdx.x * 16 + qloc;
  const int b = n >> 13;
  const float4 q = xyzw[n];
  const float4 p = make_float4(-2.f * q.x, -2.f * q.y, -2.f * q.z, q.w);
  const float4* base = xyzw + b * NN;
  float a[KK];
#pragma unroll
  for (int i = 0; i < KK; ++i) a[i] = 3.4e38f;
  const int j0 = s * 64;
#pragma unroll 4
  for (int i = 0; i < 64; ++i) {
    const float4 c = base[(j0 + i) * 8];
    const float d = distq(p, c);
#pragma unroll
    for (int k = KK - 1; k >= 1; --k) a[k] = med3f(d, a[k - 1], a[k]);
    a[0] = fminf(d, a[0]);
  }
#pragma unroll
  for (int i = 0; i < KK; ++i) part[qloc][s][i] = a[i];
  __syncthreads();
  if (s < 4) {
#pragma unroll
    for (int ss = 1; ss < 4; ++ss)
#pragma unroll
      for (int i = 0; i < KK; ++i) {
        const float d = part[qloc][s + ss * 4][i];
#pragma unroll
        for (int k = KK - 1; k >= 1; --k) a[k] = med3f(d, a[k - 1], a[k]);
        a[0] = fminf(d, a[0]);
      }
#pragma unroll
    for (int i = 0; i < KK; ++i) part[qloc][s][i] = a[i];
  }
  __syncthreads();
  if (s == 0) {
#pragma unroll
    for (int ss = 1; ss < 4; ++ss)
#pragma unroll
      for (int i = 0; i < KK; ++i) {
        const float d = part[qloc][ss][i];
#pragma unroll
        for (int k = KK - 1; k >= 1; --k) a[k] = med3f(d, a[k - 1], a[k]);
        a[0] = fminf(d, a[0]);
      }
    const float t = a[KK - 1];
    thr[n] = t + (5e-4f + 4e-5f * fabsf(t));  // covers both screen epsilons
  }
}

// ---------------- KNN B: atomic-free collect (thread owns (query,group)) ------
__global__ __launch_bounds__(256) void k_collect(const float4* __restrict__ xyzw,
                                                 const float* __restrict__ thr,
                                                 u32* __restrict__ cnt8,
                                                 u32* __restrict__ list) {
  __shared__ float4 pts[GPTS];
  const int tid = threadIdx.x;
  const int n = blockIdx.x * 256 + tid;
  const int b = n >> 13;
  const int g = blockIdx.y;
  const int m0 = g * GPTS;
#pragma unroll
  for (int i = 0; i < GPTS / 256; ++i)
    pts[i * 256 + tid] = xyzw[b * NN + m0 + i * 256 + tid];
  const float4 q = xyzw[n];
  const float4 p = make_float4(-2.f * q.x, -2.f * q.y, -2.f * q.z, q.w);
  const float tn = thr[n];
  __syncthreads();
  u32* seg = list + ((size_t)n * GRP + g) * GCAP;
  int cnt = 0;
#pragma unroll 4
  for (int mi = 0; mi < GPTS; ++mi) {
    const float d = distq(p, pts[mi]);  // LDS broadcast read
    if (d <= tn) {
      if (cnt < GCAP) seg[cnt] = (u32)(m0 + mi);
      ++cnt;
    }
  }
  cnt8[n * GRP + g] = (u32)cnt;
}

// ---------------- KNN C: exact finalize over ~128 collected ----------------
__global__ __launch_bounds__(256) void k_fin(const float4* __restrict__ xyzw,
                                             const u32* __restrict__ cnt8,
                                             const u32* __restrict__ list,
                                             int* __restrict__ idx) {
  __shared__ double part[16][16][16];
  const int tid = threadIdx.x;
  const int qloc = tid & 15;
  const int s = tid >> 4;
  const int n = blockIdx.x * 16 + qloc;
  const int b = n >> 13;
  const float4 q = xyzw[n];
  const int cn = (int)cnt8[n * GRP + s];
  const int cl = (cn < GCAP) ? cn : GCAP;
  const u32* L = list + ((size_t)n * GRP + s) * GCAP;
  double keys[KK];
#pragma unroll
  for (int i = 0; i < KK; ++i) keys[i] = __longlong_as_double(0x7FEFFFFFFFFFFFFFLL);
  for (int j = 0; j < cl; ++j) {
    const u32 m = L[j];
    const float d = distf(q, xyzw[b * NN + m]);
    u64 kb_ = ((u64)__float_as_uint(d) << 32) | m;
    double kd = __longlong_as_double((long long)kb_);
    if (kd < keys[KK - 1]) {
#pragma unroll
      for (int i = 0; i < KK; ++i) {
        double lo = fmin(keys[i], kd);
        kd = fmax(keys[i], kd);
        keys[i] = lo;
      }
    }
  }
#pragma unroll
  for (int i = 0; i < KK; ++i) part[qloc][s][i] = keys[i];
  __syncthreads();
  if (s < 4) {
#pragma unroll
    for (int ss = 1; ss < 4; ++ss)
#pragma unroll
      for (int i = 0; i < KK; ++i) {
        double kd = part[qloc][s + ss * 4][i];
        if (kd < keys[KK - 1]) {
#pragma unroll
          for (int k = 0; k < KK; ++k) {
            double lo = fmin(keys[k], kd);
            kd = fmax(keys[k], kd);
            keys[k] = lo;
          }
        }
      }
#pragma unroll
    for (int i = 0; i < KK; ++i) part[qloc][s][i] = keys[i];
  }
  __syncthreads();
  if (s == 0) {
#pragma unroll
    for (int ss = 1; ss < 4; ++ss)
#pragma unroll
      for (int i = 0; i < KK; ++i) {
        double kd = part[qloc][ss][i];
        if (kd < keys[KK - 1]) {
#pragma unroll
          for (int k = 0; k < KK; ++k) {
            double lo = fmin(keys[k], kd);
            kd = fmax(keys[k], kd);
            keys[k] = lo;
          }
        }
      }
    bool ovf = false;
#pragma unroll
    for (int gg = 0; gg < GRP; ++gg) ovf |= (cnt8[n * GRP + gg] > GCAP);
    if (ovf) {  // pathological: exact full rescan (deterministic trigger)
#pragma unroll
      for (int i = 0; i < KK; ++i) keys[i] = __longlong_as_double(0x7FEFFFFFFFFFFFFFLL);
      for (int mi = 0; mi < NN; ++mi) {
        const float d = distf(q, xyzw[b * NN + mi]);
        u64 kb_ = ((u64)__float_as_uint(d) << 32) | (u32)mi;
        double kd = __longlong_as_double((long long)kb_);
        if (kd < keys[KK - 1]) {
#pragma unroll
          for (int k = 0; k < KK; ++k) {
            double lo = fmin(keys[k], kd);
            kd = fmax(keys[k], kd);
            keys[k] = lo;
          }
        }
      }
    }
#pragma unroll
    for (int j = 0; j < KK; ++j)
      idx[n * KK + j] = (int)((u64)__double_as_longlong(keys[j]) & 0xffffffffu);
  }
}

// ---------------- weight folding: Wd = aW1 @ Wsrc ----------------
__global__ __launch_bounds__(128) void k_fold(const float* __restrict__ aW1,
                                              const float* __restrict__ Wq,
                                              const float* __restrict__ Wk,
                                              const float* __restrict__ pW2,
                                              const float* __restrict__ pb2,
                                              float* __restrict__ WqA,
                                              float* __restrict__ WkA,
                                              float* __restrict__ WpA,
                                              float* __restrict__ tvec) {
  const int bx = blockIdx.x;
  const int j = threadIdx.x;
  if (bx == 48) {
    float s = 0.f;
    for (int i = 0; i < 128; ++i) s = fmaf(aW1[j * 128 + i], pb2[i], s);
    tvec[j] = s;
    return;
  }
  const int mat = bx >> 4;
  const int c0 = (bx & 15) * 8;
  const float* S = (mat == 0) ? Wq : (mat == 1) ? Wk : pW2;
  float* D = (mat == 0) ? WqA : (mat == 1) ? WkA : WpA;
  float acc[8];
#pragma unroll
  for (int r = 0; r < 8; ++r) acc[r] = 0.f;
  for (int i = 0; i < 128; ++i) {
    float sv = S[i * 128 + j];
#pragma unroll
    for (int r = 0; r < 8; ++r) acc[r] = fmaf(aW1[(c0 + r) * 128 + i], sv, acc[r]);
  }
#pragma unroll
  for (int r = 0; r < 8; ++r) D[(c0 + r) * 128 + j] = acc[r];
}

// ---------------- split-bf16 helpers ----------------
__device__ __forceinline__ void splitf(float a, ushort_t& h, ushort_t& l) {
  u32 ab = __float_as_uint(a);
  h = (ushort_t)(ab >> 16);
  float hif = __uint_as_float(ab & 0xffff0000u);
  l = (ushort_t)(__float_as_uint(a - hif) >> 16);
}

// pack W [128][128] fp32 -> frag-ordered split planes (7 matrices)
__global__ __launch_bounds__(256) void k_packw(
    const float* __restrict__ S0, const float* __restrict__ S1,
    const float* __restrict__ S2, const float* __restrict__ S3,
    const float* __restrict__ S4, const float* __restrict__ S5,
    const float* __restrict__ S6, ushort_t* __restrict__ Phall,
    ushort_t* __restrict__ Plall) {
  const int bx = blockIdx.x;
  const int mat = bx >> 3;
  const int T = bx & 7;
  const float* S;
  switch (mat) {
    case 0: S = S0; break;
    case 1: S = S1; break;
    case 2: S = S2; break;
    case 3: S = S3; break;
    case 4: S = S4; break;
    case 5: S = S5; break;
    default: S = S6; break;
  }
  const int tid = threadIdx.x;
  const int s = tid >> 4;
  const int lr = tid & 15;
  const int c = T * 16 + lr;
  short8v vh, vl;
#pragma unroll
  for (int e = 0; e < 8; ++e) {
    ushort_t hh, ll;
    splitf(S[c * 128 + s * 8 + e], hh, ll);
    vh[e] = (short)hh;
    vl[e] = (short)ll;
  }
  const int po = mat * 16384 + T * 2048 + s * 128 + lr * 8;
  *(short8v*)&Phall[po] = vh;
  *(short8v*)&Plall[po] = vl;
}

// stage R rows x 128 cols fp32 -> hi/lo bf16 planes in LDS, XOR-swizzled
template <int ITERS>
__device__ __forceinline__ void stage_rows(const float4* __restrict__ G4,
                                           ushort_t* Bh, ushort_t* Bl, int tid) {
#pragma unroll
  for (int i = 0; i < ITERS; ++i) {
    int f = i * 256 + tid;
    int r = f >> 5, k4 = f & 31;
    float4 v = G4[f];
    ushort_t h0, l0, h1, l1, h2, l2, h3, l3;
    splitf(v.x, h0, l0);
    splitf(v.y, h1, l1);
    splitf(v.z, h2, l2);
    splitf(v.w, h3, l3);
    int slot = k4 >> 1;
    int sub = (k4 & 1) * 4;
    int base = r * 128 + ((slot ^ (r & 15)) * 8) + sub;
    *(uint2*)&Bh[base] = make_uint2((u32)h0 | ((u32)h1 << 16), (u32)h2 | ((u32)h3 << 16));
    *(uint2*)&Bl[base] = make_uint2((u32)l0 | ((u32)l1 << 16), (u32)l2 | ((u32)l3 << 16));
  }
}

// 64-row LDS-A x GLOBAL-packed-W split GEMM (k_fused)
__device__ __forceinline__ void gemm64g(const ushort_t* ABh, const ushort_t* ABl,
                                        const ushort_t* __restrict__ Ph,
                                        const ushort_t* __restrict__ Pl,
                                        f32x4 acc[2][4], int tid) {
  const int l = tid & 63, wid = tid >> 6;
  const int wrow = wid >> 1, wcol = wid & 1;
  const int lq = l >> 4, lr = l & 15;
#pragma unroll
  for (int ks = 0; ks < 4; ++ks) {
    const int sw8 = (((ks * 4 + lq) ^ lr) * 8);
    short8v ah[2], al[2], wh[4], wl[4];
#pragma unroll
    for (int ct = 0; ct < 4; ++ct) {
      int off = (wcol * 4 + ct) * 2048 + (ks * 4 + lq) * 128 + lr * 8;
      wh[ct] = *(const short8v*)&Ph[off];
      wl[ct] = *(const short8v*)&Pl[off];
    }
#pragma unroll
    for (int rt = 0; rt < 2; ++rt) {
      int row = wrow * 32 + rt * 16 + lr;
      ah[rt] = *(const short8v*)&ABh[row * 128 + sw8];
      al[rt] = *(const short8v*)&ABl[row * 128 + sw8];
    }
    __builtin_amdgcn_s_setprio(1);
#pragma unroll
    for (int rt = 0; rt < 2; ++rt)
#pragma unroll
      for (int ct = 0; ct < 4; ++ct) {
        acc[rt][ct] = __builtin_amdgcn_mfma_f32_16x16x32_bf16(ah[rt], wh[ct], acc[rt][ct], 0, 0, 0);
        acc[rt][ct] = __builtin_amdgcn_mfma_f32_16x16x32_bf16(ah[rt], wl[ct], acc[rt][ct], 0, 0, 0);
        acc[rt][ct] = __builtin_amdgcn_mfma_f32_16x16x32_bf16(al[rt], wh[ct], acc[rt][ct], 0, 0, 0);
      }
    __builtin_amdgcn_s_setprio(0);
  }
}

// ---------------- 16-row GEMM, W streamed from packed planes (1024 blocks) ----
template <int NW>
__global__ __launch_bounds__(256) void k_mms(const float* __restrict__ A,
                                             const ushort_t* __restrict__ Phall,
                                             const ushort_t* __restrict__ Plall,
                                             int m0, float* __restrict__ C0,
                                             float* __restrict__ C1,
                                             float* __restrict__ C2) {
  __shared__ ushort_t ABh[16 * 128], ABl[16 * 128];
  const int tid = threadIdx.x;
  const int Rbase = blockIdx.x * 16;
  stage_rows<2>((const float4*)(A + (size_t)Rbase * 128), ABh, ABl, tid);
  __syncthreads();
  const int l = tid & 63, wid = tid >> 6;
  const int lq = l >> 4, lr = l & 15;
  float* Cs[3] = {C0, C1, C2};
#pragma unroll
  for (int w = 0; w < NW; ++w) {
    const ushort_t* Ph = Phall + (size_t)(m0 + w) * 16384;
    const ushort_t* Pl = Plall + (size_t)(m0 + w) * 16384;
    f32x4 acc[2];
#pragma unroll
    for (int ct = 0; ct < 2; ++ct) acc[ct] = (f32x4)0.f;
#pragma unroll
    for (int ks = 0; ks < 4; ++ks) {
      const int sw8 = (((ks * 4 + lq) ^ lr) * 8);
      short8v ah, al, wh[2], wl[2];
#pragma unroll
      for (int ct = 0; ct < 2; ++ct) {
        int off = (wid * 2 + ct) * 2048 + (ks * 4 + lq) * 128 + lr * 8;
        wh[ct] = *(const short8v*)&Ph[off];
        wl[ct] = *(const short8v*)&Pl[off];
      }
      ah = *(const short8v*)&ABh[lr * 128 + sw8];
      al = *(const short8v*)&ABl[lr * 128 + sw8];
#pragma unroll
      for (int ct = 0; ct < 2; ++ct) {
        acc[ct] = __builtin_amdgcn_mfma_f32_16x16x32_bf16(ah, wh[ct], acc[ct], 0, 0, 0);
        acc[ct] = __builtin_amdgcn_mfma_f32_16x16x32_bf16(ah, wl[ct], acc[ct], 0, 0, 0);
        acc[ct] = __builtin_amdgcn_mfma_f32_16x16x32_bf16(al, wh[ct], acc[ct], 0, 0, 0);
      }
    }
#pragma unroll
    for (int ct = 0; ct < 2; ++ct) {
      int c = (wid * 2 + ct) * 16 + lr;
#pragma unroll
      for (int reg = 0; reg < 4; ++reg) {
        int R = Rbase + lq * 4 + reg;
        Cs[w][(size_t)R * 128 + c] = acc[ct][reg];
      }
    }
  }
}

// ---------------- fused chain (64 rows / 4 queries per block) ----------------
// Final Wout projection fused in-block: O-tile (4 queries) staged into the dead
// z-plane LDS rows 0..3, mini-GEMM vs packed plane 6 -> writes d_out directly.
__global__ __launch_bounds__(256, 3) void k_fused(
    const float4* __restrict__ xyzw, const int* __restrict__ idx,
    const float* __restrict__ qbA, const float* __restrict__ kbA,
    const float* __restrict__ vb, const float* __restrict__ pW1,
    const float* __restrict__ pb1, const float* __restrict__ pg,
    const float* __restrict__ pbeta, const float* __restrict__ pm,
    const float* __restrict__ pv, const float* __restrict__ pb2,
    const float* __restrict__ ab1, const float* __restrict__ ag,
    const float* __restrict__ abeta, const float* __restrict__ am,
    const float* __restrict__ av, const float* __restrict__ ab2,
    const float* __restrict__ tvec, const ushort_t* __restrict__ Phall,
    const ushort_t* __restrict__ Plall, float* __restrict__ out) {
  __shared__ ushort_t ABh[64 * 128], ABl[64 * 128];
  __shared__ float4 fW1[128];
  __shared__ float sA[128], tA[128], pB2[128], aB2[128];
  __shared__ int idxs[64];
  const int tid = threadIdx.x;
  const int Qbase = blockIdx.x * 4;
  const int b = Qbase >> 13;

  if (tid < 64) idxs[tid] = idx[Qbase * KK + tid];
  if (tid < 128) {
    int c = tid;
    float s1 = pg[c] / sqrtf(pv[c] + EPSV);
    fW1[c] = make_float4(pW1[c * 3] * s1, pW1[c * 3 + 1] * s1, pW1[c * 3 + 2] * s1,
                         (pb1[c] - pm[c]) * s1 + pbeta[c]);
    float s2 = ag[c] / sqrtf(av[c] + EPSV);
    sA[c] = s2;
    tA[c] = fmaf(s2, ab1[c] + tvec[c] - am[c], abeta[c]);
    pB2[c] = pb2[c];
    aB2[c] = ab2[c];
  }
  __syncthreads();

  // h1 tile (64 rows) -> A planes
  {
    int r = tid >> 2, qq = tid & 3;
    int Q = Qbase + (r >> 4);
    int m = idxs[r];
    float4 pq = xyzw[Q];
    float4 pn = xyzw[b * NN + m];
    float rx = pn.x - pq.x, ry = pn.y - pq.y, rz = pn.z - pq.z;
#pragma unroll
    for (int g = 0; g < 4; ++g) {
      short8v vh, vl;
      int c0 = qq * 32 + g * 8;
#pragma unroll
      for (int e = 0; e < 8; ++e) {
        float4 w = fW1[c0 + e];
        float h = fmaxf(fmaf(rz, w.z, fmaf(ry, w.y, fmaf(rx, w.x, w.w))), 0.f);
        ushort_t hh, ll;
        splitf(h, hh, ll);
        vh[e] = (short)hh;
        vl[e] = (short)ll;
      }
      int sw = (c0 >> 3) ^ (r & 15);
      *(short8v*)&ABh[r * 128 + sw * 8] = vh;
      *(short8v*)&ABl[r * 128 + sw * 8] = vl;
    }
  }
  __syncthreads();

  const int l = tid & 63, wid = tid >> 6;
  const int wrow = wid >> 1, wcol = wid & 1;
  const int lq = l >> 4, lr = l & 15;

  // GEMM0a: pos = h1 @ pW2^T (held); GEMM0b: posA = h1 @ WpA^T (held)
  f32x4 pos_[2][4], pa_[2][4];
#pragma unroll
  for (int rt = 0; rt < 2; ++rt)
#pragma unroll
    for (int ct = 0; ct < 4; ++ct) {
      pos_[rt][ct] = (f32x4)0.f;
      pa_[rt][ct] = (f32x4)0.f;
    }
  gemm64g(ABh, ABl, Phall, Plall, pos_, tid);
  gemm64g(ABh, ABl, Phall + 16384, Plall + 16384, pa_, tid);
  __syncthreads();

  // z = relu(s * (qA_gather - kA_gather + posA) + t) -> A planes
#pragma unroll
  for (int rt = 0; rt < 2; ++rt) {
    int qi_loc = wrow * 2 + rt;
    int Q = Qbase + qi_loc;
    int mr[4];
#pragma unroll
    for (int reg = 0; reg < 4; ++reg) mr[reg] = b * NN + idxs[qi_loc * 16 + lq * 4 + reg];
#pragma unroll
    for (int ct = 0; ct < 4; ++ct) {
      int c = wcol * 64 + ct * 16 + lr;
      float qv = qbA[(size_t)Q * 128 + c];
      float sc = sA[c], tc = tA[c];
#pragma unroll
      for (int reg = 0; reg < 4; ++reg) {
        float u = qv - kbA[(size_t)mr[reg] * 128 + c] + pa_[rt][ct][reg];
        float z = fmaxf(fmaf(u, sc, tc), 0.f);
        ushort_t hh, ll;
        splitf(z, hh, ll);
        int R15 = lq * 4 + reg;
        int row = wrow * 32 + rt * 16 + R15;
        int base = row * 128 + (((c >> 3) ^ R15) * 8) + (c & 7);
        ABh[base] = hh;
        ABl[base] = ll;
      }
    }
  }
  __syncthreads();

  // GEMM2: logits = z @ aW2^T (+ab2); softmax over 16 neighbors -> oo[rt][ct]
  f32x4 acc[2][4];
#pragma unroll
  for (int rt = 0; rt < 2; ++rt)
#pragma unroll
    for (int ct = 0; ct < 4; ++ct) acc[rt][ct] = (f32x4)0.f;
  gemm64g(ABh, ABl, Phall + 32768, Plall + 32768, acc, tid);

  float oo[2][4];
#pragma unroll
  for (int rt = 0; rt < 2; ++rt) {
    int qi_loc = wrow * 2 + rt;
    int mr[4];
#pragma unroll
    for (int reg = 0; reg < 4; ++reg) mr[reg] = b * NN + idxs[qi_loc * 16 + lq * 4 + reg];
#pragma unroll
    for (int ct = 0; ct < 4; ++ct) {
      int c = wcol * 64 + ct * 16 + lr;
      float ab2v = aB2[c];
      float lg[4];
#pragma unroll
      for (int reg = 0; reg < 4; ++reg) lg[reg] = acc[rt][ct][reg] + ab2v;
      float mx = fmaxf(fmaxf(lg[0], lg[1]), fmaxf(lg[2], lg[3]));
      mx = fmaxf(mx, __shfl_xor(mx, 16));
      mx = fmaxf(mx, __shfl_xor(mx, 32));
      float s = 0.f, o = 0.f;
      float pb2v = pB2[c];
#pragma unroll
      for (int reg = 0; reg < 4; ++reg) {
        float e_ = __expf(lg[reg] - mx);
        s += e_;
        float vv = vb[(size_t)mr[reg] * 128 + c] + pos_[rt][ct][reg] + pb2v;
        o = fmaf(e_, vv, o);
      }
      s += __shfl_xor(s, 16);
      s += __shfl_xor(s, 32);
      o += __shfl_xor(o, 16);
      o += __shfl_xor(o, 32);
      oo[rt][ct] = o / s;  // uniform across lq after reductions
    }
  }

  // O-tile (4 queries x 128) -> A-plane rows 0..3 (rows 4..15 hold stale finite
  // z values; their MFMA outputs are simply never stored).
  __syncthreads();  // all waves finished reading the z-tile
  if (lq == 0) {
#pragma unroll
    for (int rt = 0; rt < 2; ++rt) {
      int row = wrow * 2 + rt;
#pragma unroll
      for (int ct = 0; ct < 4; ++ct) {
        int c = wcol * 64 + ct * 16 + lr;
        ushort_t hh, ll;
        splitf(oo[rt][ct], hh, ll);
        int base = row * 128 + (((c >> 3) ^ row) * 8) + (c & 7);
        ABh[base] = hh;
        ABl[base] = ll;
      }
    }
  }
  __syncthreads();

  // final: out[Q] = O @ Wout^T (packed plane 6); same split order as k_mms.
  const ushort_t* Ph6 = Phall + 6 * 16384;
  const ushort_t* Pl6 = Plall + 6 * 16384;
  f32x4 fo[2];
  fo[0] = (f32x4)0.f;
  fo[1] = (f32x4)0.f;
#pragma unroll
  for (int ks = 0; ks < 4; ++ks) {
    const int sw8 = (((ks * 4 + lq) ^ lr) * 8);
    short8v ah = *(const short8v*)&ABh[lr * 128 + sw8];
    short8v al = *(const short8v*)&ABl[lr * 128 + sw8];
#pragma unroll
    for (int ct = 0; ct < 2; ++ct) {
      int off2 = (wid * 2 + ct) * 2048 + (ks * 4 + lq) * 128 + lr * 8;
      short8v wh = *(const short8v*)&Ph6[off2];
      short8v wl = *(const short8v*)&Pl6[off2];
      fo[ct] = __builtin_amdgcn_mfma_f32_16x16x32_bf16(ah, wh, fo[ct], 0, 0, 0);
      fo[ct] = __builtin_amdgcn_mfma_f32_16x16x32_bf16(ah, wl, fo[ct], 0, 0, 0);
      fo[ct] = __builtin_amdgcn_mfma_f32_16x16x32_bf16(al, wh, fo[ct], 0, 0, 0);
    }
  }
  if (lq == 0) {
#pragma unroll
    for (int ct = 0; ct < 2; ++ct) {
      int c = (wid * 2 + ct) * 16 + lr;
#pragma unroll
      for (int reg = 0; reg < 4; ++reg)
        out[(size_t)(Qbase + reg) * 128 + c] = fo[ct][reg];
    }
  }
}

// ---------------- host launch ----------------
extern "C" void kernel_launch(void* const* d_in, const int* in_sizes, int n_in,
                              void* d_out, int out_size, void* d_ws, size_t ws_size,
                              hipStream_t stream) {
  const float* xyz = (const float*)d_in[0];
  const float* feat = (const float*)d_in[1];
  const float* Wq = (const float*)d_in[2];
  const float* Wk = (const float*)d_in[3];
  const float* Wv = (const float*)d_in[4];
  const float* pW1 = (const float*)d_in[5];
  const float* pb1 = (const float*)d_in[6];
  const float* pg = (const float*)d_in[7];
  const float* pbeta = (const float*)d_in[8];
  const float* pmean = (const float*)d_in[9];
  const float* pvar = (const float*)d_in[10];
  const float* pW2 = (const float*)d_in[11];
  const float* pb2 = (const float*)d_in[12];
  const float* aW1 = (const float*)d_in[13];
  const float* ab1 = (const float*)d_in[14];
  const float* ag = (const float*)d_in[15];
  const float* abeta = (const float*)d_in[16];
  const float* amean = (const float*)d_in[17];
  const float* avar = (const float*)d_in[18];
  const float* aW2 = (const float*)d_in[19];
  const float* ab2 = (const float*)d_in[20];
  const float* Wout = (const float*)d_in[21];
  float* out = (float*)d_out;
  char* ws = (char*)d_ws;

  size_t off = 0;
  auto alloc = [&](size_t bytes) {
    size_t r = off;
    off += (bytes + 255) & ~(size_t)255;
    return r;
  };
  float4* xyzw = (float4*)(ws + alloc((size_t)BB * NN * 16));
  int* idx = (int*)(ws + alloc((size_t)BB * NN * KK * 4));
  size_t o_qb = alloc((size_t)BB * NN * CC * 4);
  size_t o_kb = alloc((size_t)BB * NN * CC * 4);
  size_t o_vb = alloc((size_t)BB * NN * CC * 4);
  size_t o_ob = alloc((size_t)BB * NN * CC * 4);  // keeps list span intact
  float* qbA = (float*)(ws + o_qb);
  float* kbA = (float*)(ws + o_kb);
  float* vb = (float*)(ws + o_vb);
  (void)o_ob;
  // KNN list aliases qbA..(o_ob end): 16384 * GRP(16) * GCAP(32) * 4B = 32 MB
  u32* list = (u32*)(ws + o_qb);
  // folded weights + packed planes + thresholds + counts (live whole run)
  float* WqA = (float*)(ws + alloc(128 * 128 * 4));
  float* WkA = (float*)(ws + alloc(128 * 128 * 4));
  float* WpA = (float*)(ws + alloc(128 * 128 * 4));
  float* tvec = (float*)(ws + alloc(128 * 4));
  ushort_t* Phall = (ushort_t*)(ws + alloc(7 * 16384 * 2));
  ushort_t* Plall = (ushort_t*)(ws + alloc(7 * 16384 * 2));
  float* thrbuf = (float*)(ws + alloc((size_t)BB * NN * 4));
  u32* cnt8 = (u32*)(ws + alloc((size_t)BB * NN * GRP * 4));

  k_prep<<<(BB * NN) / 256, 256, 0, stream>>>(xyz, xyzw);
  k_fold<<<49, 128, 0, stream>>>(aW1, Wq, Wk, pW2, pb2, WqA, WkA, WpA, tvec);
  // planes: 0=pW2 1=WpA 2=aW2 3=WqA 4=WkA 5=Wv 6=Wout
  k_packw<<<56, 256, 0, stream>>>(pW2, WpA, aW2, WqA, WkA, Wv, Wout, Phall, Plall);

  k_thr<<<(BB * NN) / 16, 256, 0, stream>>>(xyzw, thrbuf);
  k_collect<<<dim3((BB * NN) / 256, GRP), 256, 0, stream>>>(xyzw, thrbuf, cnt8, list);
  k_fin<<<(BB * NN) / 16, 256, 0, stream>>>(xyzw, cnt8, list, idx);

  k_mms<3><<<(BB * NN) / 16, 256, 0, stream>>>(feat, Phall, Plall, 3, qbA, kbA, vb);

  k_fused<<<(BB * NN * KK) / 64, 256, 0, stream>>>(
      xyzw, idx, qbA, kbA, vb, pW1, pb1, pg, pbeta, pmean, pvar, pb2, ab1, ag,
      abeta, amean, avar, ab2, tvec, Phall, Plall, out);
}